// Round 1
// baseline (169.324 us; speedup 1.0000x reference)
//
#include <hip/hip_runtime.h>
#include <hip/hip_bf16.h>
#include <stdint.h>

typedef _Float16 half8 __attribute__((ext_vector_type(8)));
typedef _Float16 half4 __attribute__((ext_vector_type(4)));
typedef float f32x4 __attribute__((ext_vector_type(4)));

#define N_ROWS 4096
#define DIM 1024
#define KCLS 32
#define MARGIN_F 0.3f

// ---------------- global -> LDS direct staging (16B per lane) ----------------
typedef const __attribute__((address_space(1))) void GASV;
typedef __attribute__((address_space(3))) void LASV;

__device__ __forceinline__ void gload_lds16(const void* g, void* l) {
    __builtin_amdgcn_global_load_lds((GASV*)g, (LASV*)l, 16, 0, 0);
}

// ---------------- prep: sq, f16 convert, prediction argmax ----------------
__global__ __launch_bounds__(256) void prep_kernel(
    const float* __restrict__ inputs, const float* __restrict__ prediction,
    _Float16* __restrict__ xh, float* __restrict__ sq, int* __restrict__ pred_cls)
{
    int wid = threadIdx.x >> 6, lane = threadIdx.x & 63;
    int r = blockIdx.x * 4 + wid;
    const float* row = inputs + (size_t)r * DIM;
    _Float16* hrow = xh + (size_t)r * DIM;
    float s = 0.f;
#pragma unroll
    for (int c = 0; c < 4; ++c) {
        int idx = lane * 4 + c * 256;
        float4 v = *(const float4*)(row + idx);
        s += v.x * v.x + v.y * v.y + v.z * v.z + v.w * v.w;
        half4 h;
        h.x = (_Float16)v.x; h.y = (_Float16)v.y;
        h.z = (_Float16)v.z; h.w = (_Float16)v.w;
        *(half4*)(hrow + idx) = h;
    }
#pragma unroll
    for (int off = 32; off; off >>= 1) s += __shfl_xor(s, off);

    // argmax over K=32 classes; tie -> lowest index (stable, matches jnp.argmax)
    unsigned long long key = 0ull;
    if (lane < KCLS) {
        unsigned b = __float_as_uint(prediction[(size_t)r * KCLS + lane]);
        unsigned u = (b & 0x80000000u) ? ~b : (b | 0x80000000u); // monotone map
        key = ((unsigned long long)u << 32) | (unsigned)(KCLS - 1 - lane);
    }
#pragma unroll
    for (int off = 32; off; off >>= 1) {
        unsigned long long o = __shfl_xor(key, off);
        if (o > key) key = o;
    }
    if (lane == 0) {
        sq[r] = s;
        pred_cls[r] = KCLS - 1 - (int)(key & 0xFFFFFFFFu);
    }
}

// ---------------- f16 MFMA GEMM: dot[i][j] = X_i . X_j ----------------
// 128x128 tile, BK=32, 4 waves (2x2), each wave 64x64 via 4x4 16x16x32 frags.
__global__ __launch_bounds__(256) void gemm_kernel(
    const _Float16* __restrict__ X, float* __restrict__ out, int rb0)
{
    __shared__ __align__(16) _Float16 As[128 * 32];
    __shared__ __align__(16) _Float16 Bs[128 * 32];
    int tid = threadIdx.x;
    int bx = blockIdx.x, by = blockIdx.y;
    int srow = tid >> 2;            // 0..63
    int scol = (tid & 3) * 8;       // 0,8,16,24
    const _Float16* gA0 = X + (size_t)(rb0 + bx * 128 + srow) * DIM + scol;
    const _Float16* gB0 = X + (size_t)(by * 128 + srow) * DIM + scol;
    const _Float16* gA1 = gA0 + (size_t)64 * DIM;
    const _Float16* gB1 = gB0 + (size_t)64 * DIM;
    _Float16* lA0 = As + tid * 8;
    _Float16* lA1 = As + 64 * 32 + tid * 8;
    _Float16* lB0 = Bs + tid * 8;
    _Float16* lB1 = Bs + 64 * 32 + tid * 8;

    int wid = tid >> 6, lane = tid & 63;
    int wr = (wid >> 1) * 64, wc = (wid & 1) * 64;
    int fr = lane & 15, fk = (lane >> 4) * 8;

    f32x4 acc[4][4];
#pragma unroll
    for (int m = 0; m < 4; ++m)
#pragma unroll
        for (int n = 0; n < 4; ++n) acc[m][n] = (f32x4){0.f, 0.f, 0.f, 0.f};

    for (int k0 = 0; k0 < DIM; k0 += 32) {
        gload_lds16(gA0 + k0, lA0);
        gload_lds16(gA1 + k0, lA1);
        gload_lds16(gB0 + k0, lB0);
        gload_lds16(gB1 + k0, lB1);
        __syncthreads();
        half8 a[4], b[4];
#pragma unroll
        for (int m = 0; m < 4; ++m) a[m] = *(const half8*)(As + (wr + m * 16 + fr) * 32 + fk);
#pragma unroll
        for (int n = 0; n < 4; ++n) b[n] = *(const half8*)(Bs + (wc + n * 16 + fr) * 32 + fk);
#pragma unroll
        for (int m = 0; m < 4; ++m)
#pragma unroll
            for (int n = 0; n < 4; ++n)
                acc[m][n] = __builtin_amdgcn_mfma_f32_16x16x32_f16(a[m], b[n], acc[m][n], 0, 0, 0);
        __syncthreads();
    }
    // C/D layout: col = lane&15, row = (lane>>4)*4 + reg   [guide §3, m89-verified]
    int orow_base = bx * 128 + wr + (lane >> 4) * 4;
    int ocol_base = by * 128 + wc + fr;
#pragma unroll
    for (int m = 0; m < 4; ++m)
#pragma unroll
        for (int n = 0; n < 4; ++n)
#pragma unroll
            for (int q = 0; q < 4; ++q)
                out[(size_t)(orow_base + m * 16 + q) * N_ROWS + (ocol_base + n * 16)] = acc[m][n][q];
}

// ---------------- per-row selection + case logic ----------------
// one block (256 thr) per row; keys are bit patterns of clamped d^2 (monotone w/ dist)
__global__ __launch_bounds__(256) void select_kernel(
    const float* __restrict__ dot, const float* __restrict__ sq,
    const int* __restrict__ targets, const float* __restrict__ prob,
    const int* __restrict__ pred_cls, const float* __restrict__ thr_p,
    int rb0, float* __restrict__ per_term, int* __restrict__ corr_flag)
{
    __shared__ unsigned negk[N_ROWS];   // 16 KB
    __shared__ unsigned posk[N_ROWS];   // 16 KB
    __shared__ unsigned long long red[4];
    __shared__ unsigned selNb[12]; __shared__ int selNi[12];
    __shared__ unsigned selPb[7];  __shared__ int selPi[7];

    int t = threadIdx.x;
    int lane = t & 63, wid = t >> 6;
    int rloc = blockIdx.x;
    int r = rb0 + rloc;
    int tr = targets[r];
    float sqr = sq[r];
    const float* drow = dot + (size_t)rloc * N_ROWS;

#pragma unroll 4
    for (int i = t; i < N_ROWS; i += 256) {
        float d2 = sqr + sq[i] - 2.f * drow[i];
        float d2c = fmaxf(d2, 1e-12f);          // >0 -> bits are order-preserving
        unsigned b = __float_as_uint(d2c);
        bool same = (targets[i] == tr);
        negk[i] = same ? 0x7F800000u : b;       // +inf sentinel for min
        posk[i] = same ? b : 0u;                // 0 sentinel for max
    }
    __syncthreads();

    // 12 rounds: global argmin over negk (tie -> lower index, = stable argsort)
    for (int rd = 0; rd < 12; ++rd) {
        unsigned long long best = ~0ull;
#pragma unroll 4
        for (int i = t; i < N_ROWS; i += 256) {
            unsigned long long p = ((unsigned long long)negk[i] << 32) | (unsigned)i;
            if (p < best) best = p;
        }
#pragma unroll
        for (int off = 32; off; off >>= 1) {
            unsigned long long o = __shfl_xor(best, off);
            if (o < best) best = o;
        }
        if (lane == 0) red[wid] = best;
        __syncthreads();
        if (t == 0) {
            unsigned long long b0 = red[0];
            if (red[1] < b0) b0 = red[1];
            if (red[2] < b0) b0 = red[2];
            if (red[3] < b0) b0 = red[3];
            int idx = (int)(b0 & 0xFFFFFFFFu);
            selNi[rd] = idx; selNb[rd] = (unsigned)(b0 >> 32);
            negk[idx] = 0x7F800000u;            // remove
        }
        __syncthreads();
    }
    // 7 rounds: global argmax over posk (tie -> lower index)
    for (int rd = 0; rd < 7; ++rd) {
        unsigned long long best = 0ull;
#pragma unroll 4
        for (int i = t; i < N_ROWS; i += 256) {
            unsigned long long p = ((unsigned long long)posk[i] << 32) | (unsigned)(N_ROWS - 1 - i);
            if (p > best) best = p;
        }
#pragma unroll
        for (int off = 32; off; off >>= 1) {
            unsigned long long o = __shfl_xor(best, off);
            if (o > best) best = o;
        }
        if (lane == 0) red[wid] = best;
        __syncthreads();
        if (t == 0) {
            unsigned long long b0 = red[0];
            if (red[1] > b0) b0 = red[1];
            if (red[2] > b0) b0 = red[2];
            if (red[3] > b0) b0 = red[3];
            int idx = N_ROWS - 1 - (int)(b0 & 0xFFFFFFFFu);
            selPi[rd] = idx; selPb[rd] = (unsigned)(b0 >> 32);
            posk[idx] = 0u;                     // remove
        }
        __syncthreads();
    }

    if (t == 0) {
        float thr = *thr_p;
        float d_ap = sqrtf(__uint_as_float(selPb[0]));
        float d_an = sqrtf(__uint_as_float(selNb[0]));
        int hp = selPi[0], hn = selNi[0];
        bool cp = prob[hp] >= thr;
        bool cn = prob[hn] >= thr;
        bool fn = (pred_cls[hn] == tr);
        // d_nn: first confident among neg ranks 1..10, else rank 11
        float d_nn = sqrtf(__uint_as_float(selNb[11]));
        for (int k = 1; k <= 10; ++k) {
            if (prob[selNi[k]] >= thr) { d_nn = sqrtf(__uint_as_float(selNb[k])); break; }
        }
        // d_np: first confident among pos ranks 1..5, else rank 6
        float d_np = sqrtf(__uint_as_float(selPb[6]));
        for (int k = 1; k <= 5; ++k) {
            if (prob[selPi[k]] >= thr) { d_np = sqrtf(__uint_as_float(selPb[k])); break; }
        }
        float e1p = __expf(d_ap), e2p = __expf(d_an);
        float w1 = (e1p * d_ap + e2p * d_an) / (e1p + e2p);
        float e1n = __expf(-d_ap), e2n = __expf(-d_an);
        float w0 = (e1n * d_ap + e2n * d_an) / (e1n + e2n + 1e-6f);
        bool case_b = cp && !cn && fn;
        bool case_cd = !cp && (cn || !fn);
        bool inv = !cp && !cn && fn;
        float ap = case_b ? w1 : (case_cd ? d_np : d_ap);
        float an = case_b ? d_nn : (case_cd ? w0 : d_an);
        float per = inv ? fmaxf(an - ap + MARGIN_F, 0.f)
                        : fmaxf(ap - an + MARGIN_F, 0.f);
        per_term[r] = per;
        corr_flag[r] = (an >= ap) ? 1 : 0;
    }
}

// ---------------- final deterministic reduction ----------------
__global__ __launch_bounds__(256) void finalize_kernel(
    const float* __restrict__ per_term, const int* __restrict__ corr_flag,
    const float* __restrict__ prob, const float* __restrict__ thr_p,
    float* __restrict__ out)
{
    __shared__ float sred[4]; __shared__ int cred[4]; __shared__ int nred[4];
    float thr = *thr_p;
    int t = threadIdx.x, lane = t & 63, wid = t >> 6;
    float s = 0.f; int c = 0, n = 0;
    for (int i = t; i < N_ROWS; i += 256) {
        if (prob[i] >= thr) {
            s += per_term[i];
            c += corr_flag[i];
            n += 1;
        }
    }
#pragma unroll
    for (int off = 32; off; off >>= 1) {
        s += __shfl_xor(s, off);
        c += __shfl_xor(c, off);
        n += __shfl_xor(n, off);
    }
    if (lane == 0) { sred[wid] = s; cred[wid] = c; nred[wid] = n; }
    __syncthreads();
    if (t == 0) {
        float ss = sred[0] + sred[1] + sred[2] + sred[3];
        int cc = cred[0] + cred[1] + cred[2] + cred[3];
        int nn = nred[0] + nred[1] + nred[2] + nred[3];
        float loss = (nn > 0) ? ss / (float)nn : 0.f;
        out[0] = loss;
        out[1] = (float)cc;
        out[2] = (float)nn;
    }
}

// ---------------- launch ----------------
extern "C" void kernel_launch(void* const* d_in, const int* in_sizes, int n_in,
                              void* d_out, int out_size, void* d_ws, size_t ws_size,
                              hipStream_t stream)
{
    const float* inputs     = (const float*)d_in[0];
    const float* prediction = (const float*)d_in[1];
    const int*   targets    = (const int*)d_in[2];
    // d_in[3] = true_targets: unused by the reference
    const float* prob       = (const float*)d_in[4];
    const float* thr        = (const float*)d_in[5];
    float* out = (float*)d_out;

    char* ws = (char*)d_ws;
    size_t off = 0;
    auto alloc = [&](size_t bytes) -> char* {
        char* p = ws + off;
        off = (off + bytes + 255) & ~(size_t)255;
        return p;
    };
    _Float16* xh     = (_Float16*)alloc((size_t)N_ROWS * DIM * sizeof(_Float16)); // 8 MB
    float* sq        = (float*)alloc((size_t)N_ROWS * 4);
    int*   pred_cls  = (int*)alloc((size_t)N_ROWS * 4);
    float* per_term  = (float*)alloc((size_t)N_ROWS * 4);
    int*   corr_flag = (int*)alloc((size_t)N_ROWS * 4);

    // adaptive row-block for the dot tile (power of two, >=128)
    size_t avail = (ws_size > off) ? (ws_size - off) : 0;
    size_t rowbytes = (size_t)N_ROWS * 4;
    int RB = 128;
    while (RB * 2 <= N_ROWS && (size_t)(RB * 2) * rowbytes <= avail) RB *= 2;
    float* dotbuf = (float*)alloc((size_t)RB * rowbytes);

    hipLaunchKernelGGL(prep_kernel, dim3(N_ROWS / 4), dim3(256), 0, stream,
                       inputs, prediction, xh, sq, pred_cls);
    for (int rb0 = 0; rb0 < N_ROWS; rb0 += RB) {
        hipLaunchKernelGGL(gemm_kernel, dim3(RB / 128, N_ROWS / 128), dim3(256), 0, stream,
                           xh, dotbuf, rb0);
        hipLaunchKernelGGL(select_kernel, dim3(RB), dim3(256), 0, stream,
                           dotbuf, sq, targets, prob, pred_cls, thr, rb0,
                           per_term, corr_flag);
    }
    hipLaunchKernelGGL(finalize_kernel, dim3(1), dim3(256), 0, stream,
                       per_term, corr_flag, prob, thr, out);
}

// Round 2
// 143.246 us; speedup vs baseline: 1.1820x; 1.1820x over previous
//
#include <hip/hip_runtime.h>
#include <hip/hip_bf16.h>
#include <stdint.h>

typedef _Float16 half8 __attribute__((ext_vector_type(8)));
typedef _Float16 half4 __attribute__((ext_vector_type(4)));
typedef float f32x4 __attribute__((ext_vector_type(4)));
typedef unsigned long long u64;

#define N_ROWS 4096
#define DIM 1024
#define KCLS 32
#define MARGIN_F 0.3f
#define SENTN 0xFFFFFFFFFFFFFFFFull

// ---------------- global -> LDS direct staging (16B per lane) ----------------
typedef const __attribute__((address_space(1))) void GASV;
typedef __attribute__((address_space(3))) void LASV;

__device__ __forceinline__ void gload_lds16(const void* g, void* l) {
    __builtin_amdgcn_global_load_lds((GASV*)g, (LASV*)l, 16, 0, 0);
}

// ---------------- prep: sq, f16 convert, prediction argmax ----------------
__global__ __launch_bounds__(256) void prep_kernel(
    const float* __restrict__ inputs, const float* __restrict__ prediction,
    _Float16* __restrict__ xh, float* __restrict__ sq, int* __restrict__ pred_cls)
{
    int wid = threadIdx.x >> 6, lane = threadIdx.x & 63;
    int r = blockIdx.x * 4 + wid;
    const float* row = inputs + (size_t)r * DIM;
    _Float16* hrow = xh + (size_t)r * DIM;
    float s = 0.f;
#pragma unroll
    for (int c = 0; c < 4; ++c) {
        int idx = lane * 4 + c * 256;
        float4 v = *(const float4*)(row + idx);
        s += v.x * v.x + v.y * v.y + v.z * v.z + v.w * v.w;
        half4 h;
        h.x = (_Float16)v.x; h.y = (_Float16)v.y;
        h.z = (_Float16)v.z; h.w = (_Float16)v.w;
        *(half4*)(hrow + idx) = h;
    }
#pragma unroll
    for (int off = 32; off; off >>= 1) s += __shfl_xor(s, off);

    u64 key = 0ull;
    if (lane < KCLS) {
        unsigned b = __float_as_uint(prediction[(size_t)r * KCLS + lane]);
        unsigned u = (b & 0x80000000u) ? ~b : (b | 0x80000000u);
        key = ((u64)u << 32) | (unsigned)(KCLS - 1 - lane);
    }
#pragma unroll
    for (int off = 32; off; off >>= 1) {
        u64 o = __shfl_xor(key, off);
        if (o > key) key = o;
    }
    if (lane == 0) {
        sq[r] = s;
        pred_cls[r] = KCLS - 1 - (int)(key & 0xFFFFFFFFu);
    }
}

// ---------------- f16 MFMA GEMM ----------------
__global__ __launch_bounds__(256) void gemm_kernel(
    const _Float16* __restrict__ X, float* __restrict__ out, int rb0)
{
    __shared__ __align__(16) _Float16 As[128 * 32];
    __shared__ __align__(16) _Float16 Bs[128 * 32];
    int tid = threadIdx.x;
    int bx = blockIdx.x, by = blockIdx.y;
    int srow = tid >> 2;
    int scol = (tid & 3) * 8;
    const _Float16* gA0 = X + (size_t)(rb0 + bx * 128 + srow) * DIM + scol;
    const _Float16* gB0 = X + (size_t)(by * 128 + srow) * DIM + scol;
    const _Float16* gA1 = gA0 + (size_t)64 * DIM;
    const _Float16* gB1 = gB0 + (size_t)64 * DIM;
    _Float16* lA0 = As + tid * 8;
    _Float16* lA1 = As + 64 * 32 + tid * 8;
    _Float16* lB0 = Bs + tid * 8;
    _Float16* lB1 = Bs + 64 * 32 + tid * 8;

    int wid = tid >> 6, lane = tid & 63;
    int wr = (wid >> 1) * 64, wc = (wid & 1) * 64;
    int fr = lane & 15, fk = (lane >> 4) * 8;

    f32x4 acc[4][4];
#pragma unroll
    for (int m = 0; m < 4; ++m)
#pragma unroll
        for (int n = 0; n < 4; ++n) acc[m][n] = (f32x4){0.f, 0.f, 0.f, 0.f};

    for (int k0 = 0; k0 < DIM; k0 += 32) {
        gload_lds16(gA0 + k0, lA0);
        gload_lds16(gA1 + k0, lA1);
        gload_lds16(gB0 + k0, lB0);
        gload_lds16(gB1 + k0, lB1);
        __syncthreads();
        half8 a[4], b[4];
#pragma unroll
        for (int m = 0; m < 4; ++m) a[m] = *(const half8*)(As + (wr + m * 16 + fr) * 32 + fk);
#pragma unroll
        for (int n = 0; n < 4; ++n) b[n] = *(const half8*)(Bs + (wc + n * 16 + fr) * 32 + fk);
#pragma unroll
        for (int m = 0; m < 4; ++m)
#pragma unroll
            for (int n = 0; n < 4; ++n)
                acc[m][n] = __builtin_amdgcn_mfma_f32_16x16x32_f16(a[m], b[n], acc[m][n], 0, 0, 0);
        __syncthreads();
    }
    int orow_base = bx * 128 + wr + (lane >> 4) * 4;
    int ocol_base = by * 128 + wc + fr;
#pragma unroll
    for (int m = 0; m < 4; ++m)
#pragma unroll
        for (int n = 0; n < 4; ++n)
#pragma unroll
            for (int q = 0; q < 4; ++q)
                out[(size_t)(orow_base + m * 16 + q) * N_ROWS + (ocol_base + n * 16)] = acc[m][n][q];
}

// ---------------- per-row selection, single-pass + pruned exact top-k ----------------
__global__ __launch_bounds__(256) void select_kernel(
    const float* __restrict__ dot, const float* __restrict__ sq,
    const int* __restrict__ targets, const float* __restrict__ prob,
    const int* __restrict__ pred_cls, const float* __restrict__ thr_p,
    int rb0, float* __restrict__ per_term, int* __restrict__ corr_flag)
{
    __shared__ unsigned keyv[N_ROWS];        // 16 KB: raw monotone d^2 bits
    __shared__ u64 samemask[N_ROWS / 64];    // 512 B
    __shared__ u64 Tn[4], Tp[4];
    __shared__ u64 negCand[256];
    __shared__ u64 posCand[256];
    __shared__ unsigned cnts[2];
    __shared__ u64 selN[12], selP[7];
    __shared__ u64 red[4];

    int t = threadIdx.x, lane = t & 63, w = t >> 6;
    int rloc = blockIdx.x, r = rb0 + rloc;
    int tr = targets[r];
    float sqr = sq[r];
    const float* drow = dot + (size_t)rloc * N_ROWS;

    // init
    negCand[t] = SENTN;
    posCand[t] = 0ull;
    if (t < 2) cnts[t] = 0u;

    // phase 1: one pass; keys to LDS, per-thread min/max, same bitmask
    u64 mneg = SENTN, mpos = 0ull;
#pragma unroll
    for (int c = 0; c < 16; ++c) {
        int i = t + 256 * c;
        float d2 = fmaxf(sqr + sq[i] - 2.f * drow[i], 1e-12f);
        unsigned bits = __float_as_uint(d2);
        keyv[i] = bits;
        bool same = (targets[i] == tr);
        u64 bal = __ballot(same);
        if (lane == 0) samemask[c * 4 + w] = bal;
        u64 nk = same ? SENTN : (((u64)bits << 32) | (unsigned)i);
        u64 pk = same ? (((u64)bits << 32) | (unsigned)(N_ROWS - 1 - i)) : 0ull;
        mneg = nk < mneg ? nk : mneg;
        mpos = pk > mpos ? pk : mpos;
    }

    // phase 2: per-wave 3rd-smallest min (neg) and 2nd-largest max (pos)
    u64 T3 = SENTN;
#pragma unroll
    for (int rd = 0; rd < 3; ++rd) {
        u64 b = mneg;
#pragma unroll
        for (int off = 32; off; off >>= 1) {
            u64 o = __shfl_xor(b, off);
            b = o < b ? o : b;
        }
        T3 = b;
        if (mneg == b) mneg = SENTN;
    }
    u64 P2 = 0ull;
#pragma unroll
    for (int rd = 0; rd < 2; ++rd) {
        u64 b = mpos;
#pragma unroll
        for (int off = 32; off; off >>= 1) {
            u64 o = __shfl_xor(b, off);
            b = o > b ? o : b;
        }
        P2 = b;
        if (mpos == b) mpos = 0ull;
    }
    if (lane == 0) { Tn[w] = T3; Tp[w] = P2; }
    __syncthreads();

    u64 Tneg = Tn[0];
    Tneg = Tn[1] > Tneg ? Tn[1] : Tneg;
    Tneg = Tn[2] > Tneg ? Tn[2] : Tneg;
    Tneg = Tn[3] > Tneg ? Tn[3] : Tneg;
    u64 Tpos = Tp[0];
    Tpos = Tp[1] < Tpos ? Tp[1] : Tpos;
    Tpos = Tp[2] < Tpos ? Tp[2] : Tpos;
    Tpos = Tp[3] < Tpos ? Tp[3] : Tpos;

    // phase 3: candidate append
    if (Tneg != SENTN && Tpos != 0ull) {
#pragma unroll
        for (int c = 0; c < 16; ++c) {
            int i = t + 256 * c;
            unsigned bits = keyv[i];
            bool same = (samemask[c * 4 + w] >> lane) & 1ull;
            u64 nk = same ? SENTN : (((u64)bits << 32) | (unsigned)i);
            if (nk <= Tneg) {
                unsigned s = atomicAdd(&cnts[0], 1u);
                if (s < 256u) negCand[s] = nk;
            }
            u64 pk = same ? (((u64)bits << 32) | (unsigned)(N_ROWS - 1 - i)) : 0ull;
            if (pk != 0ull && pk >= Tpos) {
                unsigned s = atomicAdd(&cnts[1], 1u);
                if (s < 256u) posCand[s] = pk;
            }
        }
    }
    __syncthreads();

    unsigned nneg = cnts[0], npos = cnts[1];
    bool fb = (Tneg == SENTN) || (Tpos == 0ull) ||
              (nneg > 256u) || (npos > 256u) || (nneg < 12u) || (npos < 7u);

    if (!fb) {
        // phase 5a: wave 0 extracts sorted top-12 negatives from <=256 candidates
        if (w == 0) {
            u64 k0 = negCand[lane], k1 = negCand[lane + 64],
                k2 = negCand[lane + 128], k3 = negCand[lane + 192];
#pragma unroll
            for (int rd = 0; rd < 12; ++rd) {
                u64 b = k0 < k1 ? k0 : k1;
                u64 b2 = k2 < k3 ? k2 : k3;
                b = b2 < b ? b2 : b;
#pragma unroll
                for (int off = 32; off; off >>= 1) {
                    u64 o = __shfl_xor(b, off);
                    b = o < b ? o : b;
                }
                if (lane == 0) selN[rd] = b;
                if (k0 == b) k0 = SENTN;
                if (k1 == b) k1 = SENTN;
                if (k2 == b) k2 = SENTN;
                if (k3 == b) k3 = SENTN;
            }
        } else if (w == 1) {
            // phase 5b: wave 1 extracts sorted top-7 positives
            u64 k0 = posCand[lane], k1 = posCand[lane + 64],
                k2 = posCand[lane + 128], k3 = posCand[lane + 192];
#pragma unroll
            for (int rd = 0; rd < 7; ++rd) {
                u64 b = k0 > k1 ? k0 : k1;
                u64 b2 = k2 > k3 ? k2 : k3;
                b = b2 > b ? b2 : b;
#pragma unroll
                for (int off = 32; off; off >>= 1) {
                    u64 o = __shfl_xor(b, off);
                    b = o > b ? o : b;
                }
                if (lane == 0) selP[rd] = b;
                if (k0 == b) k0 = 0ull;
                if (k1 == b) k1 = 0ull;
                if (k2 == b) k2 = 0ull;
                if (k3 == b) k3 = 0ull;
            }
        }
    } else {
        // fallback: exact full extraction (degenerate data only)
        for (int rd = 0; rd < 12; ++rd) {
            u64 best = SENTN;
            for (int c = 0; c < 16; ++c) {
                int i = t + 256 * c;
                unsigned bits = keyv[i];
                bool same = (samemask[c * 4 + w] >> lane) & 1ull;
                u64 nk = (!same && bits != 0x7F800000u)
                             ? (((u64)bits << 32) | (unsigned)i) : SENTN;
                best = nk < best ? nk : best;
            }
#pragma unroll
            for (int off = 32; off; off >>= 1) {
                u64 o = __shfl_xor(best, off);
                best = o < best ? o : best;
            }
            if (lane == 0) red[w] = best;
            __syncthreads();
            if (t == 0) {
                u64 b0 = red[0];
                b0 = red[1] < b0 ? red[1] : b0;
                b0 = red[2] < b0 ? red[2] : b0;
                b0 = red[3] < b0 ? red[3] : b0;
                selN[rd] = b0;
                if (b0 != SENTN) keyv[(unsigned)(b0 & 0xFFFFFFFFull) & (N_ROWS - 1)] = 0x7F800000u;
            }
            __syncthreads();
        }
        for (int rd = 0; rd < 7; ++rd) {
            u64 best = 0ull;
            for (int c = 0; c < 16; ++c) {
                int i = t + 256 * c;
                unsigned bits = keyv[i];
                bool same = (samemask[c * 4 + w] >> lane) & 1ull;
                u64 pk = (same && bits != 0u)
                             ? (((u64)bits << 32) | (unsigned)(N_ROWS - 1 - i)) : 0ull;
                best = pk > best ? pk : best;
            }
#pragma unroll
            for (int off = 32; off; off >>= 1) {
                u64 o = __shfl_xor(best, off);
                best = o > best ? o : best;
            }
            if (lane == 0) red[w] = best;
            __syncthreads();
            if (t == 0) {
                u64 b0 = red[0];
                b0 = red[1] > b0 ? red[1] : b0;
                b0 = red[2] > b0 ? red[2] : b0;
                b0 = red[3] > b0 ? red[3] : b0;
                selP[rd] = b0;
                if (b0 != 0ull)
                    keyv[(unsigned)(N_ROWS - 1 - (b0 & 0xFFFFFFFFull)) & (N_ROWS - 1)] = 0u;
            }
            __syncthreads();
        }
    }
    __syncthreads();

    if (t == 0) {
        float thr = *thr_p;
        u64 sp0 = selP[0], sn0 = selN[0];
        float d_ap = sqrtf(__uint_as_float((unsigned)(sp0 >> 32)));
        float d_an = sqrtf(__uint_as_float((unsigned)(sn0 >> 32)));
        int hp = (N_ROWS - 1 - (int)(sp0 & 0xFFFFFFFFull)) & (N_ROWS - 1);
        int hn = ((int)(sn0 & 0xFFFFFFFFull)) & (N_ROWS - 1);
        bool cp = prob[hp] >= thr;
        bool cn = prob[hn] >= thr;
        bool fn = (pred_cls[hn] == tr);
        float d_nn = sqrtf(__uint_as_float((unsigned)(selN[11] >> 32)));
        for (int k = 1; k <= 10; ++k) {
            int c = ((int)(selN[k] & 0xFFFFFFFFull)) & (N_ROWS - 1);
            if (prob[c] >= thr) { d_nn = sqrtf(__uint_as_float((unsigned)(selN[k] >> 32))); break; }
        }
        float d_np = sqrtf(__uint_as_float((unsigned)(selP[6] >> 32)));
        for (int k = 1; k <= 5; ++k) {
            int c = (N_ROWS - 1 - (int)(selP[k] & 0xFFFFFFFFull)) & (N_ROWS - 1);
            if (prob[c] >= thr) { d_np = sqrtf(__uint_as_float((unsigned)(selP[k] >> 32))); break; }
        }
        float e1p = __expf(d_ap), e2p = __expf(d_an);
        float w1 = (e1p * d_ap + e2p * d_an) / (e1p + e2p);
        float e1n = __expf(-d_ap), e2n = __expf(-d_an);
        float w0 = (e1n * d_ap + e2n * d_an) / (e1n + e2n + 1e-6f);
        bool case_b = cp && !cn && fn;
        bool case_cd = !cp && (cn || !fn);
        bool inv = !cp && !cn && fn;
        float ap = case_b ? w1 : (case_cd ? d_np : d_ap);
        float an = case_b ? d_nn : (case_cd ? w0 : d_an);
        float per = inv ? fmaxf(an - ap + MARGIN_F, 0.f)
                        : fmaxf(ap - an + MARGIN_F, 0.f);
        per_term[r] = per;
        corr_flag[r] = (an >= ap) ? 1 : 0;
    }
}

// ---------------- final deterministic reduction ----------------
__global__ __launch_bounds__(256) void finalize_kernel(
    const float* __restrict__ per_term, const int* __restrict__ corr_flag,
    const float* __restrict__ prob, const float* __restrict__ thr_p,
    float* __restrict__ out)
{
    __shared__ float sred[4]; __shared__ int cred[4]; __shared__ int nred[4];
    float thr = *thr_p;
    int t = threadIdx.x, lane = t & 63, wid = t >> 6;
    float s = 0.f; int c = 0, n = 0;
    for (int i = t; i < N_ROWS; i += 256) {
        if (prob[i] >= thr) {
            s += per_term[i];
            c += corr_flag[i];
            n += 1;
        }
    }
#pragma unroll
    for (int off = 32; off; off >>= 1) {
        s += __shfl_xor(s, off);
        c += __shfl_xor(c, off);
        n += __shfl_xor(n, off);
    }
    if (lane == 0) { sred[wid] = s; cred[wid] = c; nred[wid] = n; }
    __syncthreads();
    if (t == 0) {
        float ss = sred[0] + sred[1] + sred[2] + sred[3];
        int cc = cred[0] + cred[1] + cred[2] + cred[3];
        int nn = nred[0] + nred[1] + nred[2] + nred[3];
        float loss = (nn > 0) ? ss / (float)nn : 0.f;
        out[0] = loss;
        out[1] = (float)cc;
        out[2] = (float)nn;
    }
}

// ---------------- launch ----------------
extern "C" void kernel_launch(void* const* d_in, const int* in_sizes, int n_in,
                              void* d_out, int out_size, void* d_ws, size_t ws_size,
                              hipStream_t stream)
{
    const float* inputs     = (const float*)d_in[0];
    const float* prediction = (const float*)d_in[1];
    const int*   targets    = (const int*)d_in[2];
    const float* prob       = (const float*)d_in[4];
    const float* thr        = (const float*)d_in[5];
    float* out = (float*)d_out;

    char* ws = (char*)d_ws;
    size_t off = 0;
    auto alloc = [&](size_t bytes) -> char* {
        char* p = ws + off;
        off = (off + bytes + 255) & ~(size_t)255;
        return p;
    };
    _Float16* xh     = (_Float16*)alloc((size_t)N_ROWS * DIM * sizeof(_Float16));
    float* sq        = (float*)alloc((size_t)N_ROWS * 4);
    int*   pred_cls  = (int*)alloc((size_t)N_ROWS * 4);
    float* per_term  = (float*)alloc((size_t)N_ROWS * 4);
    int*   corr_flag = (int*)alloc((size_t)N_ROWS * 4);

    size_t avail = (ws_size > off) ? (ws_size - off) : 0;
    size_t rowbytes = (size_t)N_ROWS * 4;
    int RB = 128;
    while (RB * 2 <= N_ROWS && (size_t)(RB * 2) * rowbytes <= avail) RB *= 2;
    float* dotbuf = (float*)alloc((size_t)RB * rowbytes);

    hipLaunchKernelGGL(prep_kernel, dim3(N_ROWS / 4), dim3(256), 0, stream,
                       inputs, prediction, xh, sq, pred_cls);
    for (int rb0 = 0; rb0 < N_ROWS; rb0 += RB) {
        hipLaunchKernelGGL(gemm_kernel, dim3(RB / 128, N_ROWS / 128), dim3(256), 0, stream,
                           xh, dotbuf, rb0);
        hipLaunchKernelGGL(select_kernel, dim3(RB), dim3(256), 0, stream,
                           dotbuf, sq, targets, prob, pred_cls, thr, rb0,
                           per_term, corr_flag);
    }
    hipLaunchKernelGGL(finalize_kernel, dim3(1), dim3(256), 0, stream,
                       per_term, corr_flag, prob, thr, out);
}